// Round 4
// baseline (221.847 us; speedup 1.0000x reference)
//
#include <hip/hip_runtime.h>
#include <cstdint>
#include <cstddef>

#define DEVFN __device__ __forceinline__

typedef float f32x4 __attribute__((ext_vector_type(4)));

namespace {
constexpr int kB  = 4,  kN  = 1,  kD = 118, kFH = 32, kFW = 88, kC = 80;
constexpr int kIH = 256, kIW = 704;
constexpr int kNX = 360, kNY = 360;
constexpr int kCELLS   = kNX * kNY;               // 129,600
constexpr int kOutPerB = kC * kCELLS;             // 10,368,000
constexpr int kBDW     = kB * kN * kD * kFW;      // 41,536 (b,d,w) triples
constexpr int kCQ      = kC / 4;                  // 20 channel quads
constexpr int kNITEMS  = kBDW * kCQ;              // 830,720
// fallback (R2) config
constexpr int kWSPLIT  = 2;
constexpr int kWTILE   = kFW / kWSPLIT;           // 44
constexpr int kITEMS   = kWTILE * kCQ;            // 880
constexpr int kNBLK    = kB * kN * kD * kWSPLIT;  // 944
}

// ---------- fast zero fill (rocclr fillBuffer is ~0.7 TB/s; this hits BW) ----
__global__ __launch_bounds__(256)
void zero_kernel(f32x4* __restrict__ o4, int n4)
{
  const int stride = gridDim.x * 256;
  const f32x4 z = {0.f, 0.f, 0.f, 0.f};
  for (int i = blockIdx.x * 256 + threadIdx.x; i < n4; i += stride)
    o4[i] = z;
}

// ---------- f64 geometry helpers (bitwise-identical to R2/R3) ----------
DEVFN void inv3(const double m[9], double o[9]) {
  double a = m[0], b = m[1], c = m[2];
  double d = m[3], e = m[4], f = m[5];
  double g = m[6], h = m[7], i = m[8];
  double A = e * i - f * h;
  double B = f * g - d * i;
  double C = d * h - e * g;
  double det = a * A + b * B + c * C;
  double id = 1.0 / det;
  o[0] = A * id;              o[1] = (c * h - b * i) * id;  o[2] = (b * f - c * e) * id;
  o[3] = B * id;              o[4] = (a * i - c * g) * id;  o[5] = (c * d - a * f) * id;
  o[6] = C * id;              o[7] = (b * g - a * h) * id;  o[8] = (a * e - b * d) * id;
}

DEVFN void mm3(const double a[9], const double b[9], double o[9]) {
  #pragma unroll
  for (int i = 0; i < 3; i++)
    #pragma unroll
    for (int j = 0; j < 3; j++)
      o[i * 3 + j] = a[i * 3] * b[j] + a[i * 3 + 1] * b[3 + j] + a[i * 3 + 2] * b[6 + j];
}

DEVFN void mv3(const double a[9], const double v[3], double o[3]) {
  #pragma unroll
  for (int i = 0; i < 3; i++)
    o[i] = a[i * 3] * v[0] + a[i * 3 + 1] * v[1] + a[i * 3 + 2] * v[2];
}

DEVFN double ys_of(int h) {
  return (h == kFH - 1) ? (double)(kIH - 1)
                        : (double)h * ((double)(kIH - 1) / (double)(kFH - 1));
}

DEVFN double xs_of(int w) {
  return (w == kFW - 1) ? (double)(kIW - 1)
                        : (double)w * ((double)(kIW - 1) / (double)(kFW - 1));
}

// fold affine chain for one bn into M[24]: Minv[0..8], post_trans[9..11], A[12..20], t[21..23]
DEVFN void fold_chain(int bn, int b,
                      const float* __restrict__ rots,
                      const float* __restrict__ trans,
                      const float* __restrict__ intrins,
                      const float* __restrict__ post_rots,
                      const float* __restrict__ post_trans,
                      const float* __restrict__ l2c_rots,
                      const float* __restrict__ l2c_trans,
                      const float* __restrict__ extra_rots,
                      const float* __restrict__ extra_trans,
                      double* __restrict__ M) {
  double pr[9], it[9], rt[9], lr[9], er[9];
  #pragma unroll
  for (int k = 0; k < 9; k++) {
    pr[k] = (double)post_rots[bn * 9 + k];
    it[k] = (double)intrins[bn * 9 + k];
    rt[k] = (double)rots[bn * 9 + k];
    lr[k] = (double)l2c_rots[b * 9 + k];
    er[k] = (double)extra_rots[b * 9 + k];
  }
  double Minv[9], Ai[9], Li[9], C1[9], C2[9], A[9];
  inv3(pr, Minv); inv3(it, Ai); inv3(lr, Li);
  mm3(rt, Ai, C1); mm3(Li, C1, C2); mm3(er, C2, A);
  double tv[3], t2[3], t3[3];
  #pragma unroll
  for (int k = 0; k < 3; k++)
    tv[k] = (double)trans[bn * 3 + k] - (double)l2c_trans[b * 3 + k];
  mv3(Li, tv, t2); mv3(er, t2, t3);
  #pragma unroll
  for (int k = 0; k < 9; k++) { M[k] = Minv[k]; M[12 + k] = A[k]; }
  #pragma unroll
  for (int k = 0; k < 3; k++) {
    M[9 + k]  = (double)post_trans[bn * 3 + k];
    M[21 + k] = t3[k] + (double)extra_trans[b * 3 + k];
  }
}

DEVFN int cell_offset(const double* __restrict__ M, int b,
                      double xs, double ys, double dsv) {
  const double f0 = xs - M[9], f1 = ys - M[10], f2 = dsv - M[11];
  const double v0 = M[0] * f0 + M[1] * f1 + M[2] * f2;
  const double v1 = M[3] * f0 + M[4] * f1 + M[5] * f2;
  const double v2 = M[6] * f0 + M[7] * f1 + M[8] * f2;
  const double q0 = v0 * v2, q1 = v1 * v2, q2 = v2;
  const double g0 = M[12] * q0 + M[13] * q1 + M[14] * q2 + M[21];
  const double g1 = M[15] * q0 + M[16] * q1 + M[17] * q2 + M[22];
  const double g2 = M[18] * q0 + M[19] * q1 + M[20] * q2 + M[23];
  const double lo01 = (-54.0 + 0.3 / 2.0) - 0.3 / 2.0;
  const double lo2  = (-10.0 + 20.0 / 2.0) - 20.0 / 2.0;
  const int cx = (int)((g0 - lo01) / 0.3);
  const int cy = (int)((g1 - lo01) / 0.3);
  const int cz = (int)((g2 - lo2) / 20.0);
  if (cx >= 0 && cx < kNX && cy >= 0 && cy < kNY && cz == 0)
    return b * kOutPerB + cy * kNX + cx;
  return -1;
}

// ---------- Kernel A: geometry -> {cell offset, h-mask} per (b,d,w) ----------
__global__ __launch_bounds__(256)
void geom_kernel(const float* __restrict__ x,
                 const float* __restrict__ rots,
                 const float* __restrict__ trans,
                 const float* __restrict__ intrins,
                 const float* __restrict__ post_rots,
                 const float* __restrict__ post_trans,
                 const float* __restrict__ l2c_rots,
                 const float* __restrict__ l2c_trans,
                 const float* __restrict__ extra_rots,
                 const float* __restrict__ extra_trans,
                 float* __restrict__ out,
                 int2* __restrict__ gws)
{
  __shared__ double sm[24];
  const int bn = blockIdx.y, b = bn / kN;
  if (threadIdx.x == 0)
    fold_chain(bn, b, rots, trans, intrins, post_rots, post_trans,
               l2c_rots, l2c_trans, extra_rots, extra_trans, sm);
  __syncthreads();

  const int dw = blockIdx.x * 256 + threadIdx.x;
  if (dw >= kD * kFW) return;
  const int d = dw / kFW, w = dw % kFW;
  const double xs  = xs_of(w);
  const double dsv = 1.0 + 0.5 * (double)d;

  int off_ref = -1;
  unsigned mask = 0, extra = 0;
  for (int h = 0; h < kFH; h++) {
    const int off = cell_offset(sm, b, xs, ys_of(h), dsv);
    if (off >= 0) {
      if (off_ref < 0) off_ref = off;
      if (off == off_ref) mask |= 1u << h; else extra |= 1u << h;
    }
  }
  gws[bn * kD * kFW + dw] = make_int2(off_ref, (int)mask);

  // Fallback (expected never taken): valid h in a different cell.
  while (extra) {
    const int h = __ffs(extra) - 1;
    extra &= extra - 1;
    const int off = cell_offset(sm, b, xs, ys_of(h), dsv);
    const float* px = x + ((((size_t)(bn * kD + d) * kFH + h) * kFW) + w) * kC;
    for (int c = 0; c < kC; c++)
      atomicAdd(out + off + (size_t)c * kCELLS, px[c]);
  }
}

// ---------- Kernel B: streaming masked h-reduction + one atomic burst ----------
__global__ __launch_bounds__(256)
void pool_kernel(const f32x4* __restrict__ x4,
                 const int2* __restrict__ gws,
                 float* __restrict__ out)
{
  const int item = blockIdx.x * 256 + threadIdx.x;   // 0..kNITEMS-1
  const int bdw = item / kCQ;
  const int cq  = item % kCQ;
  const int2 g  = gws[bdw];
  if (g.x < 0) return;
  const unsigned mask = (unsigned)g.y;

  const int bd = bdw / kFW, w = bdw % kFW;
  const f32x4* __restrict__ p =
      x4 + (size_t)bd * kFH * (kFW * kCQ) + w * kCQ + cq;

  f32x4 acc = {0.f, 0.f, 0.f, 0.f};
  #pragma unroll
  for (int h = 0; h < kFH; h++) {
    const float s = (float)((mask >> h) & 1u);
    const f32x4 v = __builtin_nontemporal_load(p + (size_t)h * (kFW * kCQ));
    acc.x = fmaf(v.x, s, acc.x);
    acc.y = fmaf(v.y, s, acc.y);
    acc.z = fmaf(v.z, s, acc.z);
    acc.w = fmaf(v.w, s, acc.w);
  }

  float* o = out + g.x + (size_t)(4 * cq) * kCELLS;
  atomicAdd(o,              acc.x);
  atomicAdd(o +     kCELLS, acc.y);
  atomicAdd(o + 2 * kCELLS, acc.z);
  atomicAdd(o + 3 * kCELLS, acc.w);
}

// ---------- Fallback all-in-one kernel (R2), used only if ws too small ----------
__global__ __launch_bounds__(256)
void bev_pool_kernel(const float* __restrict__ x,
                     const float* __restrict__ rots,
                     const float* __restrict__ trans,
                     const float* __restrict__ intrins,
                     const float* __restrict__ post_rots,
                     const float* __restrict__ post_trans,
                     const float* __restrict__ l2c_rots,
                     const float* __restrict__ l2c_trans,
                     const float* __restrict__ extra_rots,
                     const float* __restrict__ extra_trans,
                     float* __restrict__ out)
{
  __shared__ double sm[24];
  __shared__ int      soff[kWTILE];
  __shared__ unsigned smask[kWTILE];
  __shared__ int      s_any;

  const int bid = blockIdx.x;
  const int wt  = bid & (kWSPLIT - 1);
  const int d   = (bid / kWSPLIT) % kD;
  const int bn  = bid / (kWSPLIT * kD);
  const int b   = bn / kN;
  const int tid = threadIdx.x;

  if (tid == 0) {
    s_any = 0;
    fold_chain(bn, b, rots, trans, intrins, post_rots, post_trans,
               l2c_rots, l2c_trans, extra_rots, extra_trans, sm);
  }
  __syncthreads();

  if (tid < kWTILE) {
    const int w = wt * kWTILE + tid;
    const double xs  = xs_of(w);
    const double dsv = 1.0 + 0.5 * (double)d;
    int off_ref = -1;
    unsigned mask = 0, extra = 0;
    for (int h = 0; h < kFH; h++) {
      const int off = cell_offset(sm, b, xs, ys_of(h), dsv);
      if (off >= 0) {
        if (off_ref < 0) off_ref = off;
        if (off == off_ref) mask |= 1u << h; else extra |= 1u << h;
      }
    }
    soff[tid]  = off_ref;
    smask[tid] = mask;
    if (off_ref >= 0) s_any = 1;
    while (extra) {
      const int h = __ffs(extra) - 1;
      extra &= extra - 1;
      const int off = cell_offset(sm, b, xs, ys_of(h), dsv);
      const float* px = x + ((((size_t)(bn * kD + d) * kFH + h) * kFW) + w) * kC;
      for (int c = 0; c < kC; c++)
        atomicAdd(out + off + (size_t)c * kCELLS, px[c]);
    }
  }
  __syncthreads();
  if (!s_any) return;

  const float4* __restrict__ x4 = reinterpret_cast<const float4*>(x);
  float4 acc[4];
  int      itw[4];
  unsigned msk[4];
  bool     vld[4];
  #pragma unroll
  for (int k = 0; k < 4; k++) {
    const int item = tid + 256 * k;
    vld[k] = item < kITEMS;
    itw[k] = vld[k] ? item / kCQ : 0;
    msk[k] = vld[k] ? smask[itw[k]] : 0u;
    acc[k] = make_float4(0.f, 0.f, 0.f, 0.f);
  }
  for (int h = 0; h < kFH; h++) {
    const size_t base =
        (((size_t)(bn * kD + d) * kFH + h) * kFW + wt * kWTILE) * kCQ;
    #pragma unroll
    for (int k = 0; k < 4; k++) {
      const int item = tid + 256 * k;
      if (vld[k]) {
        const float s = (float)((msk[k] >> h) & 1u);
        const float4 v = x4[base + item];
        acc[k].x = fmaf(v.x, s, acc[k].x);
        acc[k].y = fmaf(v.y, s, acc[k].y);
        acc[k].z = fmaf(v.z, s, acc[k].z);
        acc[k].w = fmaf(v.w, s, acc[k].w);
      }
    }
  }
  #pragma unroll
  for (int k = 0; k < 4; k++) {
    if (!vld[k]) continue;
    const int off = soff[itw[k]];
    if (off < 0) continue;
    const int item = tid + 256 * k;
    const int cq = item % kCQ;
    float* o = out + off + (size_t)(4 * cq) * kCELLS;
    atomicAdd(o,              acc[k].x);
    atomicAdd(o +     kCELLS, acc[k].y);
    atomicAdd(o + 2 * kCELLS, acc[k].z);
    atomicAdd(o + 3 * kCELLS, acc[k].w);
  }
}

extern "C" void kernel_launch(void* const* d_in, const int* in_sizes, int n_in,
                              void* d_out, int out_size, void* d_ws, size_t ws_size,
                              hipStream_t stream) {
  const float* x          = (const float*)d_in[0];
  const float* rots       = (const float*)d_in[1];
  const float* trans      = (const float*)d_in[2];
  const float* intrins    = (const float*)d_in[3];
  const float* post_rots  = (const float*)d_in[4];
  const float* post_trans = (const float*)d_in[5];
  const float* l2c_rots   = (const float*)d_in[6];
  const float* l2c_trans  = (const float*)d_in[7];
  const float* extra_rots = (const float*)d_in[8];
  const float* extra_trans= (const float*)d_in[9];
  float* out = (float*)d_out;

  // Fast zero of the output (out_size is divisible by 4; guard the tail anyway)
  const int n4 = out_size / 4;
  zero_kernel<<<dim3(2048), dim3(256), 0, stream>>>((f32x4*)out, n4);
  if (out_size & 3)
    hipMemsetAsync(out + (size_t)n4 * 4, 0,
                   (size_t)(out_size & 3) * sizeof(float), stream);

  if (ws_size >= (size_t)kBDW * sizeof(int2)) {
    int2* gws = (int2*)d_ws;
    geom_kernel<<<dim3((kD * kFW + 255) / 256, kB * kN), dim3(256), 0, stream>>>(
        x, rots, trans, intrins, post_rots, post_trans,
        l2c_rots, l2c_trans, extra_rots, extra_trans, out, gws);
    pool_kernel<<<dim3(kNITEMS / 256), dim3(256), 0, stream>>>(
        (const f32x4*)x, gws, out);
  } else {
    bev_pool_kernel<<<dim3(kNBLK), dim3(256), 0, stream>>>(
        x, rots, trans, intrins, post_rots, post_trans,
        l2c_rots, l2c_trans, extra_rots, extra_trans, out);
  }
}

// Round 5
// 136.541 us; speedup vs baseline: 1.6248x; 1.6248x over previous
//
#include <hip/hip_runtime.h>
#include <cstdint>
#include <cstddef>

#define DEVFN __device__ __forceinline__

typedef float f32x4 __attribute__((ext_vector_type(4)));
typedef int   i32x4 __attribute__((ext_vector_type(4)));

namespace {
constexpr int kB  = 4,  kN  = 1,  kD = 118, kFH = 32, kFW = 88, kC = 80;
constexpr int kIH = 256, kIW = 704;
constexpr int kNX = 360, kNY = 360;
constexpr int kCELLS   = kNX * kNY;               // 129,600
constexpr int kOutPerB = kC * kCELLS;             // 10,368,000
constexpr int kBDW     = kB * kN * kD * kFW;      // 41,536 (b,d,w) triples
constexpr int kCQ      = kC / 4;                  // 20 channel quads
constexpr int kNITEMS  = kBDW * kCQ;              // 830,720
constexpr int kSLOTCAP = kBDW + 4096;             // primary allocs <= kBDW, slack for (never-seen) extras
// workspace layout (bytes)
constexpr size_t kOffNslots = 0;
constexpr size_t kOffSlotId = 1024;                                   // kB*kCELLS ints (2,073,600 B)
constexpr size_t kOffGws    = kOffSlotId + (size_t)kB * kCELLS * 4;   // kBDW int2 (332,288 B)
constexpr size_t kOffSf     = kOffGws + (size_t)kBDW * 8;             // kSLOTCAP*kC floats
constexpr size_t kWsNeed    = kOffSf + (size_t)kSLOTCAP * kC * 4;     // ~17 MB
// fallback (R2) config
constexpr int kWSPLIT = 2;
constexpr int kWTILE  = kFW / kWSPLIT;            // 44
constexpr int kITEMS  = kWTILE * kCQ;             // 880
constexpr int kNBLK   = kB * kN * kD * kWSPLIT;   // 944
}

// ---------- f64 geometry helpers (bitwise-identical to R2-R4) ----------
DEVFN void inv3(const double m[9], double o[9]) {
  double a = m[0], b = m[1], c = m[2];
  double d = m[3], e = m[4], f = m[5];
  double g = m[6], h = m[7], i = m[8];
  double A = e * i - f * h;
  double B = f * g - d * i;
  double C = d * h - e * g;
  double det = a * A + b * B + c * C;
  double id = 1.0 / det;
  o[0] = A * id;              o[1] = (c * h - b * i) * id;  o[2] = (b * f - c * e) * id;
  o[3] = B * id;              o[4] = (a * i - c * g) * id;  o[5] = (c * d - a * f) * id;
  o[6] = C * id;              o[7] = (b * g - a * h) * id;  o[8] = (a * e - b * d) * id;
}

DEVFN void mm3(const double a[9], const double b[9], double o[9]) {
  #pragma unroll
  for (int i = 0; i < 3; i++)
    #pragma unroll
    for (int j = 0; j < 3; j++)
      o[i * 3 + j] = a[i * 3] * b[j] + a[i * 3 + 1] * b[3 + j] + a[i * 3 + 2] * b[6 + j];
}

DEVFN void mv3(const double a[9], const double v[3], double o[3]) {
  #pragma unroll
  for (int i = 0; i < 3; i++)
    o[i] = a[i * 3] * v[0] + a[i * 3 + 1] * v[1] + a[i * 3 + 2] * v[2];
}

DEVFN double ys_of(int h) {
  return (h == kFH - 1) ? (double)(kIH - 1)
                        : (double)h * ((double)(kIH - 1) / (double)(kFH - 1));
}

DEVFN double xs_of(int w) {
  return (w == kFW - 1) ? (double)(kIW - 1)
                        : (double)w * ((double)(kIW - 1) / (double)(kFW - 1));
}

DEVFN void fold_chain(int bn, int b,
                      const float* __restrict__ rots,
                      const float* __restrict__ trans,
                      const float* __restrict__ intrins,
                      const float* __restrict__ post_rots,
                      const float* __restrict__ post_trans,
                      const float* __restrict__ l2c_rots,
                      const float* __restrict__ l2c_trans,
                      const float* __restrict__ extra_rots,
                      const float* __restrict__ extra_trans,
                      double* __restrict__ M) {
  double pr[9], it[9], rt[9], lr[9], er[9];
  #pragma unroll
  for (int k = 0; k < 9; k++) {
    pr[k] = (double)post_rots[bn * 9 + k];
    it[k] = (double)intrins[bn * 9 + k];
    rt[k] = (double)rots[bn * 9 + k];
    lr[k] = (double)l2c_rots[b * 9 + k];
    er[k] = (double)extra_rots[b * 9 + k];
  }
  double Minv[9], Ai[9], Li[9], C1[9], C2[9], A[9];
  inv3(pr, Minv); inv3(it, Ai); inv3(lr, Li);
  mm3(rt, Ai, C1); mm3(Li, C1, C2); mm3(er, C2, A);
  double tv[3], t2[3], t3[3];
  #pragma unroll
  for (int k = 0; k < 3; k++)
    tv[k] = (double)trans[bn * 3 + k] - (double)l2c_trans[b * 3 + k];
  mv3(Li, tv, t2); mv3(er, t2, t3);
  #pragma unroll
  for (int k = 0; k < 9; k++) { M[k] = Minv[k]; M[12 + k] = A[k]; }
  #pragma unroll
  for (int k = 0; k < 3; k++) {
    M[9 + k]  = (double)post_trans[bn * 3 + k];
    M[21 + k] = t3[k] + (double)extra_trans[b * 3 + k];
  }
}

// returns b-qualified CELL id (b*kCELLS + cy*kNX + cx) or -1; binning math identical to R2-R4
DEVFN int cell_id(const double* __restrict__ M, int b,
                  double xs, double ys, double dsv) {
  const double f0 = xs - M[9], f1 = ys - M[10], f2 = dsv - M[11];
  const double v0 = M[0] * f0 + M[1] * f1 + M[2] * f2;
  const double v1 = M[3] * f0 + M[4] * f1 + M[5] * f2;
  const double v2 = M[6] * f0 + M[7] * f1 + M[8] * f2;
  const double q0 = v0 * v2, q1 = v1 * v2, q2 = v2;
  const double g0 = M[12] * q0 + M[13] * q1 + M[14] * q2 + M[21];
  const double g1 = M[15] * q0 + M[16] * q1 + M[17] * q2 + M[22];
  const double g2 = M[18] * q0 + M[19] * q1 + M[20] * q2 + M[23];
  const double lo01 = (-54.0 + 0.3 / 2.0) - 0.3 / 2.0;
  const double lo2  = (-10.0 + 20.0 / 2.0) - 20.0 / 2.0;
  const int cx = (int)((g0 - lo01) / 0.3);
  const int cy = (int)((g1 - lo01) / 0.3);
  const int cz = (int)((g2 - lo2) / 20.0);
  if (cx >= 0 && cx < kNX && cy >= 0 && cy < kNY && cz == 0)
    return b * kCELLS + cy * kNX + cx;
  return -1;
}

// lock-free get-or-create dense slot for a cell; loser-leaked slots are zeroed & never read
DEVFN int get_slot(int* __restrict__ slotid, int cell, int* __restrict__ nslots) {
  int s = ((volatile int*)slotid)[cell];
  if (s < 0) {
    const int my = atomicAdd(nslots, 1);
    if (my < kSLOTCAP) {
      const int old = atomicCAS(&slotid[cell], -1, my);
      s = (old == -1) ? my : old;
    } else {
      s = ((volatile int*)slotid)[cell];  // unreachable (primary allocs <= kBDW < cap)
    }
  }
  return s;
}

// ---------- K0: init slotid=-1, slot_feats=0, nslots=0 ----------
__global__ __launch_bounds__(256)
void init_kernel(int* __restrict__ slotid, float* __restrict__ sf,
                 int* __restrict__ nslots)
{
  const int i0 = blockIdx.x * 256 + threadIdx.x;
  const int stride = gridDim.x * 256;
  if (i0 == 0) *nslots = 0;
  i32x4* s4 = (i32x4*)slotid;
  const int nS4 = kB * kCELLS / 4;          // 129,600
  for (int i = i0; i < nS4; i += stride) s4[i] = i32x4{-1, -1, -1, -1};
  f32x4* f4 = (f32x4*)sf;
  const int nF4 = kSLOTCAP * kC / 4;        // 912,640
  const f32x4 z = {0.f, 0.f, 0.f, 0.f};
  for (int i = i0; i < nF4; i += stride) f4[i] = z;
}

// ---------- K1: geometry -> {slot, h-mask} per (b,d,w) ----------
__global__ __launch_bounds__(256)
void geom_kernel(const float* __restrict__ x,
                 const float* __restrict__ rots,
                 const float* __restrict__ trans,
                 const float* __restrict__ intrins,
                 const float* __restrict__ post_rots,
                 const float* __restrict__ post_trans,
                 const float* __restrict__ l2c_rots,
                 const float* __restrict__ l2c_trans,
                 const float* __restrict__ extra_rots,
                 const float* __restrict__ extra_trans,
                 int* __restrict__ slotid,
                 int2* __restrict__ gws,
                 float* __restrict__ sf,
                 int* __restrict__ nslots)
{
  __shared__ double sm[24];
  const int bn = blockIdx.y, b = bn / kN;
  if (threadIdx.x == 0)
    fold_chain(bn, b, rots, trans, intrins, post_rots, post_trans,
               l2c_rots, l2c_trans, extra_rots, extra_trans, sm);
  __syncthreads();

  const int dw = blockIdx.x * 256 + threadIdx.x;
  if (dw >= kD * kFW) return;
  const int d = dw / kFW, w = dw % kFW;
  const double xs  = xs_of(w);
  const double dsv = 1.0 + 0.5 * (double)d;

  int cell_ref = -1;
  unsigned mask = 0, extra = 0;
  for (int h = 0; h < kFH; h++) {
    const int cell = cell_id(sm, b, xs, ys_of(h), dsv);
    if (cell >= 0) {
      if (cell_ref < 0) cell_ref = cell;
      if (cell == cell_ref) mask |= 1u << h; else extra |= 1u << h;
    }
  }
  int slot = -1;
  if (cell_ref >= 0) slot = get_slot(slotid, cell_ref, nslots);
  gws[bn * kD * kFW + dw] = make_int2(slot, (int)mask);

  // Fallback (expected never taken): valid h in a different cell -> scatter into its slot.
  while (extra) {
    const int h = __ffs(extra) - 1;
    extra &= extra - 1;
    const int cell2 = cell_id(sm, b, xs, ys_of(h), dsv);
    const int s2 = get_slot(slotid, cell2, nslots);
    if (s2 >= 0) {
      const float* px = x + ((((size_t)(bn * kD + d) * kFH + h) * kFW) + w) * kC;
      for (int c = 0; c < kC; c++)
        atomicAdd(sf + (size_t)s2 * kC + c, px[c]);
    }
  }
}

// ---------- K2: streaming masked h-reduction + dense atomic burst ----------
__global__ __launch_bounds__(256)
void pool_kernel(const f32x4* __restrict__ x4,
                 const int2* __restrict__ gws,
                 float* __restrict__ sf)
{
  const int item = blockIdx.x * 256 + threadIdx.x;   // 0..kNITEMS-1
  const int bdw = item / kCQ;
  const int cq  = item % kCQ;
  const int2 g  = gws[bdw];
  if (g.x < 0) return;
  const unsigned mask = (unsigned)g.y;

  const int bd = bdw / kFW, w = bdw % kFW;
  const f32x4* __restrict__ p =
      x4 + (size_t)bd * kFH * (kFW * kCQ) + w * kCQ + cq;

  f32x4 acc = {0.f, 0.f, 0.f, 0.f};
  #pragma unroll
  for (int h = 0; h < kFH; h++) {
    const float s = (float)((mask >> h) & 1u);
    const f32x4 v = __builtin_nontemporal_load(p + (size_t)h * (kFW * kCQ));
    acc.x = fmaf(v.x, s, acc.x);
    acc.y = fmaf(v.y, s, acc.y);
    acc.z = fmaf(v.z, s, acc.z);
    acc.w = fmaf(v.w, s, acc.w);
  }

  float* o = sf + (size_t)g.x * kC + 4 * cq;   // dense, L2-resident
  atomicAdd(o + 0, acc.x);
  atomicAdd(o + 1, acc.y);
  atomicAdd(o + 2, acc.z);
  atomicAdd(o + 3, acc.w);
}

// ---------- K3: expand dense slots -> full output (writes every byte once) ----------
__global__ __launch_bounds__(256)
void expand_kernel(const int* __restrict__ slotid,
                   const float* __restrict__ sf,
                   float* __restrict__ out)
{
  const int flat = blockIdx.x * 256 + threadIdx.x;   // < kB*kCELLS (exact grid)
  const int b  = flat / kCELLS;
  const int yx = flat % kCELLS;
  const int s  = slotid[flat];

  f32x4 v[kCQ];
  #pragma unroll
  for (int q = 0; q < kCQ; q++) v[q] = f32x4{0.f, 0.f, 0.f, 0.f};
  if (s >= 0) {
    const f32x4* __restrict__ f4 = (const f32x4*)(sf + (size_t)s * kC);
    #pragma unroll
    for (int q = 0; q < kCQ; q++) v[q] = f4[q];
  }

  float* o = out + (size_t)b * kOutPerB + yx;
  #pragma unroll
  for (int q = 0; q < kCQ; q++) {
    __builtin_nontemporal_store(v[q].x, o + (size_t)(4 * q + 0) * kCELLS);
    __builtin_nontemporal_store(v[q].y, o + (size_t)(4 * q + 1) * kCELLS);
    __builtin_nontemporal_store(v[q].z, o + (size_t)(4 * q + 2) * kCELLS);
    __builtin_nontemporal_store(v[q].w, o + (size_t)(4 * q + 3) * kCELLS);
  }
}

// ---------- fast zero fill (fallback path only) ----------
__global__ __launch_bounds__(256)
void zero_kernel(f32x4* __restrict__ o4, int n4)
{
  const int stride = gridDim.x * 256;
  const f32x4 z = {0.f, 0.f, 0.f, 0.f};
  for (int i = blockIdx.x * 256 + threadIdx.x; i < n4; i += stride)
    o4[i] = z;
}

// ---------- Fallback all-in-one kernel (R2), used only if ws too small ----------
__global__ __launch_bounds__(256)
void bev_pool_kernel(const float* __restrict__ x,
                     const float* __restrict__ rots,
                     const float* __restrict__ trans,
                     const float* __restrict__ intrins,
                     const float* __restrict__ post_rots,
                     const float* __restrict__ post_trans,
                     const float* __restrict__ l2c_rots,
                     const float* __restrict__ l2c_trans,
                     const float* __restrict__ extra_rots,
                     const float* __restrict__ extra_trans,
                     float* __restrict__ out)
{
  __shared__ double sm[24];
  __shared__ int      soff[kWTILE];
  __shared__ unsigned smask[kWTILE];
  __shared__ int      s_any;

  const int bid = blockIdx.x;
  const int wt  = bid & (kWSPLIT - 1);
  const int d   = (bid / kWSPLIT) % kD;
  const int bn  = bid / (kWSPLIT * kD);
  const int b   = bn / kN;
  const int tid = threadIdx.x;

  if (tid == 0) {
    s_any = 0;
    fold_chain(bn, b, rots, trans, intrins, post_rots, post_trans,
               l2c_rots, l2c_trans, extra_rots, extra_trans, sm);
  }
  __syncthreads();

  if (tid < kWTILE) {
    const int w = wt * kWTILE + tid;
    const double xs  = xs_of(w);
    const double dsv = 1.0 + 0.5 * (double)d;
    int cell_ref = -1;
    unsigned mask = 0, extra = 0;
    for (int h = 0; h < kFH; h++) {
      const int cell = cell_id(sm, b, xs, ys_of(h), dsv);
      if (cell >= 0) {
        if (cell_ref < 0) cell_ref = cell;
        if (cell == cell_ref) mask |= 1u << h; else extra |= 1u << h;
      }
    }
    // convert cell id -> out offset
    soff[tid]  = (cell_ref >= 0)
               ? (cell_ref / kCELLS) * kOutPerB + (cell_ref % kCELLS) : -1;
    smask[tid] = mask;
    if (cell_ref >= 0) s_any = 1;
    while (extra) {
      const int h = __ffs(extra) - 1;
      extra &= extra - 1;
      const int cell2 = cell_id(sm, b, xs, ys_of(h), dsv);
      const int off2 = (cell2 / kCELLS) * kOutPerB + (cell2 % kCELLS);
      const float* px = x + ((((size_t)(bn * kD + d) * kFH + h) * kFW) + w) * kC;
      for (int c = 0; c < kC; c++)
        atomicAdd(out + off2 + (size_t)c * kCELLS, px[c]);
    }
  }
  __syncthreads();
  if (!s_any) return;

  const float4* __restrict__ x4 = reinterpret_cast<const float4*>(x);
  float4 acc[4];
  int      itw[4];
  unsigned msk[4];
  bool     vld[4];
  #pragma unroll
  for (int k = 0; k < 4; k++) {
    const int item = tid + 256 * k;
    vld[k] = item < kITEMS;
    itw[k] = vld[k] ? item / kCQ : 0;
    msk[k] = vld[k] ? smask[itw[k]] : 0u;
    acc[k] = make_float4(0.f, 0.f, 0.f, 0.f);
  }
  for (int h = 0; h < kFH; h++) {
    const size_t base =
        (((size_t)(bn * kD + d) * kFH + h) * kFW + wt * kWTILE) * kCQ;
    #pragma unroll
    for (int k = 0; k < 4; k++) {
      const int item = tid + 256 * k;
      if (vld[k]) {
        const float s = (float)((msk[k] >> h) & 1u);
        const float4 v = x4[base + item];
        acc[k].x = fmaf(v.x, s, acc[k].x);
        acc[k].y = fmaf(v.y, s, acc[k].y);
        acc[k].z = fmaf(v.z, s, acc[k].z);
        acc[k].w = fmaf(v.w, s, acc[k].w);
      }
    }
  }
  #pragma unroll
  for (int k = 0; k < 4; k++) {
    if (!vld[k]) continue;
    const int off = soff[itw[k]];
    if (off < 0) continue;
    const int item = tid + 256 * k;
    const int cq = item % kCQ;
    float* o = out + off + (size_t)(4 * cq) * kCELLS;
    atomicAdd(o,              acc[k].x);
    atomicAdd(o +     kCELLS, acc[k].y);
    atomicAdd(o + 2 * kCELLS, acc[k].z);
    atomicAdd(o + 3 * kCELLS, acc[k].w);
  }
}

extern "C" void kernel_launch(void* const* d_in, const int* in_sizes, int n_in,
                              void* d_out, int out_size, void* d_ws, size_t ws_size,
                              hipStream_t stream) {
  const float* x          = (const float*)d_in[0];
  const float* rots       = (const float*)d_in[1];
  const float* trans      = (const float*)d_in[2];
  const float* intrins    = (const float*)d_in[3];
  const float* post_rots  = (const float*)d_in[4];
  const float* post_trans = (const float*)d_in[5];
  const float* l2c_rots   = (const float*)d_in[6];
  const float* l2c_trans  = (const float*)d_in[7];
  const float* extra_rots = (const float*)d_in[8];
  const float* extra_trans= (const float*)d_in[9];
  float* out = (float*)d_out;

  if (ws_size >= kWsNeed) {
    char* wsb = (char*)d_ws;
    int*  nslots = (int*) (wsb + kOffNslots);
    int*  slotid = (int*) (wsb + kOffSlotId);
    int2* gws    = (int2*)(wsb + kOffGws);
    float* sf    = (float*)(wsb + kOffSf);

    init_kernel<<<dim3(1024), dim3(256), 0, stream>>>(slotid, sf, nslots);
    geom_kernel<<<dim3((kD * kFW + 255) / 256, kB * kN), dim3(256), 0, stream>>>(
        x, rots, trans, intrins, post_rots, post_trans,
        l2c_rots, l2c_trans, extra_rots, extra_trans, slotid, gws, sf, nslots);
    pool_kernel<<<dim3(kNITEMS / 256), dim3(256), 0, stream>>>(
        (const f32x4*)x, gws, sf);
    expand_kernel<<<dim3(kB * kCELLS / 256), dim3(256), 0, stream>>>(
        slotid, sf, out);
  } else {
    const int n4 = out_size / 4;
    zero_kernel<<<dim3(2048), dim3(256), 0, stream>>>((f32x4*)out, n4);
    bev_pool_kernel<<<dim3(kNBLK), dim3(256), 0, stream>>>(
        x, rots, trans, intrins, post_rots, post_trans,
        l2c_rots, l2c_trans, extra_rots, extra_trans, out);
  }
}